// Round 1
// baseline (1635.723 us; speedup 1.0000x reference)
//
#include <hip/hip_runtime.h>

#define NN 50000
#define NE 800000
#define HD 128

// ---------------------------------------------------------------------------
// Graph prep
// ---------------------------------------------------------------------------
__global__ void k_count(const int* __restrict__ ei, float* __restrict__ deg,
                        int* __restrict__ cnt) {
    int e = blockIdx.x * 256 + threadIdx.x;
    if (e < NE) {
        atomicAdd(&deg[ei[e]], 1.0f);       // out-degree over src
        atomicAdd(&cnt[ei[NE + e]], 1);     // in-degree histogram over dst
    }
}

__global__ void k_dinv(const float* __restrict__ deg, float* __restrict__ dinv) {
    int n = blockIdx.x * 256 + threadIdx.x;
    if (n < NN) {
        float d = deg[n];
        dinv[n] = d > 0.0f ? rsqrtf(d) : 0.0f;
    }
}

__global__ __launch_bounds__(1024) void k_scan1(const int* __restrict__ cnt,
                                                int* __restrict__ rowptr,
                                                int* __restrict__ bsum) {
    __shared__ int s[1024];
    int tid = threadIdx.x;
    int gid = blockIdx.x * 1024 + tid;
    int v = (gid < NN) ? cnt[gid] : 0;
    s[tid] = v;
    __syncthreads();
    for (int off = 1; off < 1024; off <<= 1) {
        int t = 0;
        if (tid >= off) t = s[tid - off];
        __syncthreads();
        s[tid] += t;
        __syncthreads();
    }
    if (gid < NN) rowptr[gid] = s[tid] - v;       // exclusive
    if (tid == 1023) bsum[blockIdx.x] = s[1023];  // block total
}

__global__ void k_scan2(const int* __restrict__ bsum, int* __restrict__ boff,
                        int nb, int* __restrict__ rowptr) {
    if (threadIdx.x == 0 && blockIdx.x == 0) {
        int acc = 0;
        for (int i = 0; i < nb; i++) { boff[i] = acc; acc += bsum[i]; }
        rowptr[NN] = acc;  // == NE
    }
}

__global__ void k_scan3(int* __restrict__ rowptr, const int* __restrict__ boff) {
    int i = blockIdx.x * 256 + threadIdx.x;
    if (i < NN) rowptr[i] += boff[i >> 10];
}

__global__ void k_fill(const int* __restrict__ ei, const float* __restrict__ dinv,
                       const int* __restrict__ rowptr, int* __restrict__ fill,
                       int* __restrict__ col, float* __restrict__ val) {
    int e = blockIdx.x * 256 + threadIdx.x;
    if (e < NE) {
        int s = ei[e];
        int d = ei[NE + e];
        int pos = rowptr[d] + atomicAdd(&fill[d], 1);
        col[pos] = s;
        val[pos] = -dinv[s] * dinv[d];
    }
}

// ---------------------------------------------------------------------------
// Propagation (CSR gather).  out[n] = 2*sum - sub[n]  (or just sum if !sub)
// ---------------------------------------------------------------------------
__global__ void k_prop3(const float* __restrict__ h, const float* __restrict__ sub,
                        const int* __restrict__ rowptr, const int* __restrict__ col,
                        const float* __restrict__ val, float* __restrict__ out) {
    int node = blockIdx.x * 256 + threadIdx.x;
    if (node >= NN) return;
    int e0 = rowptr[node], e1 = rowptr[node + 1];
    float a0 = 0.f, a1 = 0.f, a2 = 0.f;
    for (int e = e0; e < e1; e++) {
        int s = col[e];
        float v = val[e];
        a0 += v * h[s * 3 + 0];
        a1 += v * h[s * 3 + 1];
        a2 += v * h[s * 3 + 2];
    }
    if (sub) {
        a0 = 2.f * a0 - sub[node * 3 + 0];
        a1 = 2.f * a1 - sub[node * 3 + 1];
        a2 = 2.f * a2 - sub[node * 3 + 2];
    }
    out[node * 3 + 0] = a0;
    out[node * 3 + 1] = a1;
    out[node * 3 + 2] = a2;
}

__global__ __launch_bounds__(256) void k_prop128(
        const float* __restrict__ h, const float* __restrict__ sub,
        const int* __restrict__ rowptr, const int* __restrict__ col,
        const float* __restrict__ val, float* __restrict__ out) {
    int node = blockIdx.x * 2 + (threadIdx.x >> 7);
    int f = threadIdx.x & 127;
    if (node >= NN) return;
    int e0 = rowptr[node], e1 = rowptr[node + 1];
    float acc = 0.f;
    int e = e0;
    for (; e + 1 < e1; e += 2) {
        int s0 = col[e];
        int s1 = col[e + 1];
        float v0 = val[e];
        float v1 = val[e + 1];
        float h0 = h[s0 * HD + f];
        float h1 = h[s1 * HD + f];
        acc = fmaf(v0, h0, acc);
        acc = fmaf(v1, h1, acc);
    }
    if (e < e1) {
        int s0 = col[e];
        acc = fmaf(val[e], h[s0 * HD + f], acc);
    }
    float r = sub ? (2.f * acc - sub[node * HD + f]) : acc;
    out[node * HD + f] = r;
}

// ---------------------------------------------------------------------------
// Layer-1 GEMM: [N,3] x4 Cheb terms  @ W1[4][3][128] + b, leaky relu
// ---------------------------------------------------------------------------
__global__ __launch_bounds__(256) void k_gemm1(
        const float* __restrict__ T0, const float* __restrict__ T1,
        const float* __restrict__ T2, const float* __restrict__ T3,
        const float* __restrict__ W, const float* __restrict__ bias,
        float* __restrict__ out) {
    __shared__ float Ws[12 * 128];
    __shared__ float tx[2][12];
    int t = threadIdx.x;
    for (int i = t; i < 12 * 128; i += 256) Ws[i] = W[i];
    int idx = blockIdx.x * 256 + t;
    int node = idx >> 7;
    int f = idx & 127;
    int localn = t >> 7;
    const float* Ts[4] = {T0, T1, T2, T3};
    if (f < 12 && node < NN) {
        tx[localn][f] = Ts[f / 3][node * 3 + (f % 3)];
    }
    __syncthreads();
    if (node < NN) {
        float acc = bias[f];
        #pragma unroll
        for (int c = 0; c < 12; c++) acc = fmaf(tx[localn][c], Ws[c * 128 + f], acc);
        acc = acc > 0.f ? acc : 0.01f * acc;  // leaky relu
        out[node * HD + f] = acc;
    }
}

// ---------------------------------------------------------------------------
// 128-dim GEMM: out[n,f] = act( b[f] + sum_k sum_c Txk[n,c]*W[k][c][f] )
// block tile 64 rows x 128 cols, thread tile 4x8. act: 0=none,1=leaky,2=relu
// ---------------------------------------------------------------------------
__global__ __launch_bounds__(256) void k_gemm128(
        const float* __restrict__ T0, const float* __restrict__ T1,
        const float* __restrict__ T2, const float* __restrict__ T3,
        const float* __restrict__ W, const float* __restrict__ bias,
        float* __restrict__ out, int act) {
    __shared__ float As[64][36];   // pad 36 -> conflict-free column reads
    __shared__ float Ws[32][128];
    const int t = threadIdx.x;
    const int cg = t & 15;   // 8 cols: cg*8 .. cg*8+7
    const int rg = t >> 4;   // rows rg + 16*j, j=0..3
    const int row0 = blockIdx.x * 64;

    float acc[4][8];
    #pragma unroll
    for (int j = 0; j < 4; j++)
        #pragma unroll
        for (int c = 0; c < 8; c++) acc[j][c] = 0.f;

    const float* Tbuf[4] = {T0, T1, T2, T3};
    for (int kb = 0; kb < 4; kb++) {
        const float* T = Tbuf[kb];
        for (int kc = 0; kc < 4; kc++) {
            // stage A tile: 64 rows x 32 cols
            #pragma unroll
            for (int i = 0; i < 2; i++) {
                int idx = t + 256 * i;     // 0..511
                int r = idx >> 3;          // 0..63
                int c4 = idx & 7;          // 0..7
                int row = row0 + r;
                float4 v = make_float4(0.f, 0.f, 0.f, 0.f);
                if (row < NN) v = *(const float4*)(T + row * HD + kc * 32 + c4 * 4);
                *(float4*)&As[r][c4 * 4] = v;
            }
            // stage W tile: 32 x 128
            #pragma unroll
            for (int i = 0; i < 4; i++) {
                int idx = t + 256 * i;     // 0..1023
                int k = idx >> 5;          // 0..31
                int f4 = idx & 31;         // 0..31
                *(float4*)&Ws[k][f4 * 4] =
                    *(const float4*)(W + (kb * 128 + kc * 32 + k) * 128 + f4 * 4);
            }
            __syncthreads();
            #pragma unroll 8
            for (int k = 0; k < 32; k++) {
                float4 w0 = *(const float4*)&Ws[k][cg * 8];
                float4 w1 = *(const float4*)&Ws[k][cg * 8 + 4];
                #pragma unroll
                for (int j = 0; j < 4; j++) {
                    float a = As[rg + 16 * j][k];
                    acc[j][0] = fmaf(a, w0.x, acc[j][0]);
                    acc[j][1] = fmaf(a, w0.y, acc[j][1]);
                    acc[j][2] = fmaf(a, w0.z, acc[j][2]);
                    acc[j][3] = fmaf(a, w0.w, acc[j][3]);
                    acc[j][4] = fmaf(a, w1.x, acc[j][4]);
                    acc[j][5] = fmaf(a, w1.y, acc[j][5]);
                    acc[j][6] = fmaf(a, w1.z, acc[j][6]);
                    acc[j][7] = fmaf(a, w1.w, acc[j][7]);
                }
            }
            __syncthreads();
        }
    }
    // epilogue
    float bl[8];
    #pragma unroll
    for (int c = 0; c < 8; c++) bl[c] = bias[cg * 8 + c];
    #pragma unroll
    for (int j = 0; j < 4; j++) {
        int row = row0 + rg + 16 * j;
        if (row < NN) {
            float v[8];
            #pragma unroll
            for (int c = 0; c < 8; c++) {
                float x = acc[j][c] + bl[c];
                if (act == 1) x = x > 0.f ? x : 0.01f * x;
                else if (act == 2) x = x > 0.f ? x : 0.f;
                v[c] = x;
            }
            *(float4*)(out + row * HD + cg * 8) = make_float4(v[0], v[1], v[2], v[3]);
            *(float4*)(out + row * HD + cg * 8 + 4) = make_float4(v[4], v[5], v[6], v[7]);
        }
    }
}

// ---------------------------------------------------------------------------
// BatchNorm
// ---------------------------------------------------------------------------
__global__ __launch_bounds__(128) void k_bnstats(const float* __restrict__ h,
                                                 float* __restrict__ sums) {
    int f = threadIdx.x;
    float s = 0.f, sq = 0.f;
    for (int r = blockIdx.x; r < NN; r += gridDim.x) {
        float v = h[r * HD + f];
        s += v;
        sq += v * v;
    }
    atomicAdd(&sums[f], s);
    atomicAdd(&sums[HD + f], sq);
}

__global__ __launch_bounds__(128) void k_bnfin(const float* __restrict__ sums,
                                               const float* __restrict__ g,
                                               const float* __restrict__ be,
                                               float* __restrict__ ss) {
    int f = threadIdx.x;
    float mean = sums[f] * (1.0f / NN);
    float var = sums[HD + f] * (1.0f / NN) - mean * mean;
    float sc = g[f] * rsqrtf(var + 1e-5f);
    ss[f] = sc;
    ss[HD + f] = be[f] - mean * sc;
}

__global__ void k_bnapply(float* __restrict__ h, const float* __restrict__ ss) {
    int idx = blockIdx.x * 256 + threadIdx.x;  // over NN*32 float4s
    if (idx < NN * 32) {
        int c4 = idx & 31;
        float4 v = ((float4*)h)[idx];
        float4 sc = ((const float4*)ss)[c4];
        float4 sh = ((const float4*)(ss + HD))[c4];
        v.x = fmaf(v.x, sc.x, sh.x);
        v.y = fmaf(v.y, sc.y, sh.y);
        v.z = fmaf(v.z, sc.z, sh.z);
        v.w = fmaf(v.w, sc.w, sh.w);
        ((float4*)h)[idx] = v;
    }
}

// ---------------------------------------------------------------------------
// Row L2 normalize -> d_out
// ---------------------------------------------------------------------------
__global__ __launch_bounds__(256) void k_l2norm(const float* __restrict__ h,
                                                float* __restrict__ out) {
    int row = blockIdx.x * 4 + (threadIdx.x >> 6);
    int lane = threadIdx.x & 63;
    if (row >= NN) return;
    float2 v = *(const float2*)(h + row * HD + lane * 2);
    float s = v.x * v.x + v.y * v.y;
    #pragma unroll
    for (int off = 32; off > 0; off >>= 1) s += __shfl_xor(s, off);
    float scale = 1.f / fmaxf(sqrtf(s), 1e-12f);
    *(float2*)(out + row * HD + lane * 2) = make_float2(v.x * scale, v.y * scale);
}

// ---------------------------------------------------------------------------
// Launch
// ---------------------------------------------------------------------------
extern "C" void kernel_launch(void* const* d_in, const int* in_sizes, int n_in,
                              void* d_out, int out_size, void* d_ws, size_t ws_size,
                              hipStream_t stream) {
    const float* x  = (const float*)d_in[0];
    const int*   ei = (const int*)d_in[1];
    const float* W1 = (const float*)d_in[2];
    const float* b1 = (const float*)d_in[3];
    const float* W2 = (const float*)d_in[4];
    const float* b2 = (const float*)d_in[5];
    const float* W3 = (const float*)d_in[6];
    const float* b3 = (const float*)d_in[7];
    const float* W4 = (const float*)d_in[8];
    const float* b4 = (const float*)d_in[9];
    const float* g1 = (const float*)d_in[10];
    const float* be1 = (const float*)d_in[11];
    const float* g2 = (const float*)d_in[12];
    const float* be2 = (const float*)d_in[13];
    const float* g3 = (const float*)d_in[14];
    const float* be3 = (const float*)d_in[15];
    float* outp = (float*)d_out;

    // workspace layout (256B aligned slabs)
    char* base = (char*)d_ws;
    size_t off = 0;
    auto alloc = [&](size_t bytes) -> void* {
        void* p = base + off;
        off += (bytes + 255) & ~(size_t)255;
        return p;
    };
    float* deg   = (float*)alloc(NN * 4);
    int*   cnt   = (int*)  alloc(NN * 4);
    int*   fil   = (int*)  alloc(NN * 4);
    float* dinv  = (float*)alloc(NN * 4);
    int*   rowptr= (int*)  alloc((NN + 1) * 4);
    int*   bsum  = (int*)  alloc(64 * 4);
    int*   boff  = (int*)  alloc(64 * 4);
    float* bnsum = (float*)alloc(256 * 4);
    float* ss    = (float*)alloc(256 * 4);
    int*   col   = (int*)  alloc(NE * 4);
    float* val   = (float*)alloc(NE * 4);
    float* T3a   = (float*)alloc(NN * 3 * 4);
    float* T3b   = (float*)alloc(NN * 3 * 4);
    float* T3c   = (float*)alloc(NN * 3 * 4);
    float* B0    = (float*)alloc((size_t)NN * HD * 4);
    float* B1    = (float*)alloc((size_t)NN * HD * 4);
    float* B2    = (float*)alloc((size_t)NN * HD * 4);
    float* B3    = (float*)alloc((size_t)NN * HD * 4);
    float* B4    = (float*)alloc((size_t)NN * HD * 4);

    const int gE = (NE + 255) / 256;     // 3125
    const int gN = (NN + 255) / 256;     // 196
    const int nb = (NN + 1023) / 1024;   // 49

    // ---- graph prep ----
    hipMemsetAsync(deg, 0, ((size_t)(char*)dinv - (size_t)(char*)deg), stream); // deg,cnt,fil
    k_count<<<gE, 256, 0, stream>>>(ei, deg, cnt);
    k_dinv<<<gN, 256, 0, stream>>>(deg, dinv);
    k_scan1<<<nb, 1024, 0, stream>>>(cnt, rowptr, bsum);
    k_scan2<<<1, 64, 0, stream>>>(bsum, boff, nb, rowptr);
    k_scan3<<<gN, 256, 0, stream>>>(rowptr, boff);
    k_fill<<<gE, 256, 0, stream>>>(ei, dinv, rowptr, fil, col, val);

    const int gP = (NN + 1) / 2;          // 25000 blocks, 2 nodes each
    const int gG = (NN + 63) / 64;        // 782
    const int gApply = (NN * 32 + 255) / 256;
    const int gL2 = (NN + 3) / 4;

    // ---- layer 1 (in: x [N,3]) ----
    k_prop3<<<gN, 256, 0, stream>>>(x, nullptr, rowptr, col, val, T3a);
    k_prop3<<<gN, 256, 0, stream>>>(T3a, x, rowptr, col, val, T3b);
    k_prop3<<<gN, 256, 0, stream>>>(T3b, T3a, rowptr, col, val, T3c);
    k_gemm1<<<(NN * 128 + 255) / 256, 256, 0, stream>>>(x, T3a, T3b, T3c, W1, b1, B0);
    hipMemsetAsync(bnsum, 0, 256 * 4, stream);
    k_bnstats<<<256, 128, 0, stream>>>(B0, bnsum);
    k_bnfin<<<1, 128, 0, stream>>>(bnsum, g1, be1, ss);
    k_bnapply<<<gApply, 256, 0, stream>>>(B0, ss);

    // ---- layer 2 (in: B0) ----
    k_prop128<<<gP, 256, 0, stream>>>(B0, nullptr, rowptr, col, val, B1);
    k_prop128<<<gP, 256, 0, stream>>>(B1, B0, rowptr, col, val, B2);
    k_prop128<<<gP, 256, 0, stream>>>(B2, B1, rowptr, col, val, B3);
    k_gemm128<<<gG, 256, 0, stream>>>(B0, B1, B2, B3, W2, b2, B4, 1);
    hipMemsetAsync(bnsum, 0, 256 * 4, stream);
    k_bnstats<<<256, 128, 0, stream>>>(B4, bnsum);
    k_bnfin<<<1, 128, 0, stream>>>(bnsum, g2, be2, ss);
    k_bnapply<<<gApply, 256, 0, stream>>>(B4, ss);

    // ---- layer 3 (in: B4) ----
    k_prop128<<<gP, 256, 0, stream>>>(B4, nullptr, rowptr, col, val, B0);
    k_prop128<<<gP, 256, 0, stream>>>(B0, B4, rowptr, col, val, B1);
    k_prop128<<<gP, 256, 0, stream>>>(B1, B0, rowptr, col, val, B2);
    k_gemm128<<<gG, 256, 0, stream>>>(B4, B0, B1, B2, W3, b3, B3, 2);
    hipMemsetAsync(bnsum, 0, 256 * 4, stream);
    k_bnstats<<<256, 128, 0, stream>>>(B3, bnsum);
    k_bnfin<<<1, 128, 0, stream>>>(bnsum, g3, be3, ss);
    k_bnapply<<<gApply, 256, 0, stream>>>(B3, ss);

    // ---- layer 4 (in: B3) ----
    k_prop128<<<gP, 256, 0, stream>>>(B3, nullptr, rowptr, col, val, B4);
    k_prop128<<<gP, 256, 0, stream>>>(B4, B3, rowptr, col, val, B0);
    k_prop128<<<gP, 256, 0, stream>>>(B0, B4, rowptr, col, val, B1);
    k_gemm128<<<gG, 256, 0, stream>>>(B3, B4, B0, B1, W4, b4, B2, 0);
    k_l2norm<<<gL2, 256, 0, stream>>>(B2, outp);

    (void)n_in; (void)in_sizes; (void)out_size; (void)ws_size;
}

// Round 2
// 1225.147 us; speedup vs baseline: 1.3351x; 1.3351x over previous
//
#include <hip/hip_runtime.h>

#define NN 50000
#define NE 800000
#define HD 128

// ---------------------------------------------------------------------------
// Graph prep
// ---------------------------------------------------------------------------
__global__ void k_count(const int* __restrict__ ei, float* __restrict__ deg,
                        int* __restrict__ cnt) {
    int e = blockIdx.x * 256 + threadIdx.x;
    if (e < NE) {
        atomicAdd(&deg[ei[e]], 1.0f);       // out-degree over src
        atomicAdd(&cnt[ei[NE + e]], 1);     // in-degree histogram over dst
    }
}

__global__ void k_dinv(const float* __restrict__ deg, float* __restrict__ dinv) {
    int n = blockIdx.x * 256 + threadIdx.x;
    if (n < NN) {
        float d = deg[n];
        dinv[n] = d > 0.0f ? rsqrtf(d) : 0.0f;
    }
}

__global__ __launch_bounds__(1024) void k_scan1(const int* __restrict__ cnt,
                                                int* __restrict__ rowptr,
                                                int* __restrict__ bsum) {
    __shared__ int s[1024];
    int tid = threadIdx.x;
    int gid = blockIdx.x * 1024 + tid;
    int v = (gid < NN) ? cnt[gid] : 0;
    s[tid] = v;
    __syncthreads();
    for (int off = 1; off < 1024; off <<= 1) {
        int t = 0;
        if (tid >= off) t = s[tid - off];
        __syncthreads();
        s[tid] += t;
        __syncthreads();
    }
    if (gid < NN) rowptr[gid] = s[tid] - v;       // exclusive
    if (tid == 1023) bsum[blockIdx.x] = s[1023];  // block total
}

__global__ void k_scan2(const int* __restrict__ bsum, int* __restrict__ boff,
                        int nb, int* __restrict__ rowptr) {
    if (threadIdx.x == 0 && blockIdx.x == 0) {
        int acc = 0;
        for (int i = 0; i < nb; i++) { boff[i] = acc; acc += bsum[i]; }
        rowptr[NN] = acc;  // == NE
    }
}

__global__ void k_scan3(int* __restrict__ rowptr, const int* __restrict__ boff) {
    int i = blockIdx.x * 256 + threadIdx.x;
    if (i < NN) rowptr[i] += boff[i >> 10];
}

__global__ void k_fill(const int* __restrict__ ei, const float* __restrict__ dinv,
                       const int* __restrict__ rowptr, int* __restrict__ fill,
                       int2* __restrict__ edg) {
    int e = blockIdx.x * 256 + threadIdx.x;
    if (e < NE) {
        int s = ei[e];
        int d = ei[NE + e];
        int pos = rowptr[d] + atomicAdd(&fill[d], 1);
        edg[pos] = make_int2(s, __float_as_int(-dinv[s] * dinv[d]));
    }
}

// ---------------------------------------------------------------------------
// Propagation (CSR gather).  out[n] = 2*sum - sub[n]  (or just sum if !sub)
// ---------------------------------------------------------------------------
__global__ void k_prop3(const float* __restrict__ h, const float* __restrict__ sub,
                        const int* __restrict__ rowptr, const int2* __restrict__ edg,
                        float* __restrict__ out) {
    int node = blockIdx.x * 256 + threadIdx.x;
    if (node >= NN) return;
    int e0 = rowptr[node], e1 = rowptr[node + 1];
    float a0 = 0.f, a1 = 0.f, a2 = 0.f;
    for (int e = e0; e < e1; e++) {
        int2 p = edg[e];
        int s = p.x;
        float v = __int_as_float(p.y);
        a0 += v * h[s * 3 + 0];
        a1 += v * h[s * 3 + 1];
        a2 += v * h[s * 3 + 2];
    }
    if (sub) {
        a0 = 2.f * a0 - sub[node * 3 + 0];
        a1 = 2.f * a1 - sub[node * 3 + 1];
        a2 = 2.f * a2 - sub[node * 3 + 2];
    }
    out[node * 3 + 0] = a0;
    out[node * 3 + 1] = a1;
    out[node * 3 + 2] = a2;
}

// 32 threads per node, float4 per thread (16B gathers), 4-edge unroll.
__global__ __launch_bounds__(256) void k_prop128(
        const float* __restrict__ h, const float* __restrict__ sub,
        const int* __restrict__ rowptr, const int2* __restrict__ edg,
        float* __restrict__ out) {
    int node = blockIdx.x * 8 + (threadIdx.x >> 5);
    if (node >= NN) return;
    int q4 = (threadIdx.x & 31) * 4;
    int e0 = rowptr[node], e1 = rowptr[node + 1];
    float4 a0 = {0.f, 0.f, 0.f, 0.f};
    float4 a1 = a0, a2 = a0, a3 = a0;
    int e = e0;
    for (; e + 4 <= e1; e += 4) {
        int2 p0 = edg[e];
        int2 p1 = edg[e + 1];
        int2 p2 = edg[e + 2];
        int2 p3 = edg[e + 3];
        float4 h0 = *(const float4*)(h + (p0.x << 7) + q4);
        float4 h1 = *(const float4*)(h + (p1.x << 7) + q4);
        float4 h2 = *(const float4*)(h + (p2.x << 7) + q4);
        float4 h3 = *(const float4*)(h + (p3.x << 7) + q4);
        float v0 = __int_as_float(p0.y);
        float v1 = __int_as_float(p1.y);
        float v2 = __int_as_float(p2.y);
        float v3 = __int_as_float(p3.y);
        a0.x = fmaf(v0, h0.x, a0.x); a0.y = fmaf(v0, h0.y, a0.y);
        a0.z = fmaf(v0, h0.z, a0.z); a0.w = fmaf(v0, h0.w, a0.w);
        a1.x = fmaf(v1, h1.x, a1.x); a1.y = fmaf(v1, h1.y, a1.y);
        a1.z = fmaf(v1, h1.z, a1.z); a1.w = fmaf(v1, h1.w, a1.w);
        a2.x = fmaf(v2, h2.x, a2.x); a2.y = fmaf(v2, h2.y, a2.y);
        a2.z = fmaf(v2, h2.z, a2.z); a2.w = fmaf(v2, h2.w, a2.w);
        a3.x = fmaf(v3, h3.x, a3.x); a3.y = fmaf(v3, h3.y, a3.y);
        a3.z = fmaf(v3, h3.z, a3.z); a3.w = fmaf(v3, h3.w, a3.w);
    }
    for (; e < e1; e++) {
        int2 p = edg[e];
        float4 hv = *(const float4*)(h + (p.x << 7) + q4);
        float v = __int_as_float(p.y);
        a0.x = fmaf(v, hv.x, a0.x); a0.y = fmaf(v, hv.y, a0.y);
        a0.z = fmaf(v, hv.z, a0.z); a0.w = fmaf(v, hv.w, a0.w);
    }
    float4 r;
    r.x = (a0.x + a1.x) + (a2.x + a3.x);
    r.y = (a0.y + a1.y) + (a2.y + a3.y);
    r.z = (a0.z + a1.z) + (a2.z + a3.z);
    r.w = (a0.w + a1.w) + (a2.w + a3.w);
    if (sub) {
        float4 s = *(const float4*)(sub + (node << 7) + q4);
        r.x = 2.f * r.x - s.x;
        r.y = 2.f * r.y - s.y;
        r.z = 2.f * r.z - s.z;
        r.w = 2.f * r.w - s.w;
    }
    *(float4*)(out + (node << 7) + q4) = r;
}

// ---------------------------------------------------------------------------
// Layer-1 GEMM: [N,3] x4 Cheb terms  @ W1[4][3][128] + b, leaky relu
// ---------------------------------------------------------------------------
__global__ __launch_bounds__(256) void k_gemm1(
        const float* __restrict__ T0, const float* __restrict__ T1,
        const float* __restrict__ T2, const float* __restrict__ T3,
        const float* __restrict__ W, const float* __restrict__ bias,
        float* __restrict__ out) {
    __shared__ float Ws[12 * 128];
    __shared__ float tx[2][12];
    int t = threadIdx.x;
    for (int i = t; i < 12 * 128; i += 256) Ws[i] = W[i];
    int idx = blockIdx.x * 256 + t;
    int node = idx >> 7;
    int f = idx & 127;
    int localn = t >> 7;
    const float* Ts[4] = {T0, T1, T2, T3};
    if (f < 12 && node < NN) {
        tx[localn][f] = Ts[f / 3][node * 3 + (f % 3)];
    }
    __syncthreads();
    if (node < NN) {
        float acc = bias[f];
        #pragma unroll
        for (int c = 0; c < 12; c++) acc = fmaf(tx[localn][c], Ws[c * 128 + f], acc);
        acc = acc > 0.f ? acc : 0.01f * acc;  // leaky relu
        out[node * HD + f] = acc;
    }
}

// ---------------------------------------------------------------------------
// 128-dim GEMM: out[n,f] = act( b[f] + sum_k sum_c Txk[n,c]*W[k][c][f] )
// block tile 64 rows x 128 cols, thread tile 4 rows x 8 cols.
// Column map per thread: {cg*4+j, 64+cg*4+j} -> Ws b128 reads span 64 floats
// = 2-way bank alias (free) instead of 4-way.
// act: 0=none,1=leaky,2=relu.  If gsum != nullptr, fused BN col sums/sqsums.
// ---------------------------------------------------------------------------
__global__ __launch_bounds__(256) void k_gemm128(
        const float* __restrict__ T0, const float* __restrict__ T1,
        const float* __restrict__ T2, const float* __restrict__ T3,
        const float* __restrict__ W, const float* __restrict__ bias,
        float* __restrict__ out, int act, float* __restrict__ gsum) {
    __shared__ float smem[64 * 36 + 32 * 128];  // As | Ws; reused as red[16][128]
    float (*As)[36] = (float(*)[36])smem;
    float (*Ws)[128] = (float(*)[128])(smem + 64 * 36);
    const int t = threadIdx.x;
    const int cg = t & 15;   // col groups: cg*4..cg*4+3 and 64+cg*4..64+cg*4+3
    const int rg = t >> 4;   // rows rg + 16*j, j=0..3
    const int row0 = blockIdx.x * 64;

    float acc[4][8];
    #pragma unroll
    for (int j = 0; j < 4; j++)
        #pragma unroll
        for (int c = 0; c < 8; c++) acc[j][c] = 0.f;

    const float* Tbuf[4] = {T0, T1, T2, T3};
    for (int kb = 0; kb < 4; kb++) {
        const float* T = Tbuf[kb];
        for (int kc = 0; kc < 4; kc++) {
            // stage A tile: 64 rows x 32 cols
            #pragma unroll
            for (int i = 0; i < 2; i++) {
                int idx = t + 256 * i;     // 0..511
                int r = idx >> 3;          // 0..63
                int c4 = idx & 7;          // 0..7
                int row = row0 + r;
                float4 v = make_float4(0.f, 0.f, 0.f, 0.f);
                if (row < NN) v = *(const float4*)(T + row * HD + kc * 32 + c4 * 4);
                *(float4*)&As[r][c4 * 4] = v;
            }
            // stage W tile: 32 x 128
            #pragma unroll
            for (int i = 0; i < 4; i++) {
                int idx = t + 256 * i;     // 0..1023
                int k = idx >> 5;          // 0..31
                int f4 = idx & 31;         // 0..31
                *(float4*)&Ws[k][f4 * 4] =
                    *(const float4*)(W + (kb * 128 + kc * 32 + k) * 128 + f4 * 4);
            }
            __syncthreads();
            #pragma unroll 8
            for (int k = 0; k < 32; k++) {
                float4 w0 = *(const float4*)&Ws[k][cg * 4];
                float4 w1 = *(const float4*)&Ws[k][cg * 4 + 64];
                #pragma unroll
                for (int j = 0; j < 4; j++) {
                    float a = As[rg + 16 * j][k];
                    acc[j][0] = fmaf(a, w0.x, acc[j][0]);
                    acc[j][1] = fmaf(a, w0.y, acc[j][1]);
                    acc[j][2] = fmaf(a, w0.z, acc[j][2]);
                    acc[j][3] = fmaf(a, w0.w, acc[j][3]);
                    acc[j][4] = fmaf(a, w1.x, acc[j][4]);
                    acc[j][5] = fmaf(a, w1.y, acc[j][5]);
                    acc[j][6] = fmaf(a, w1.z, acc[j][6]);
                    acc[j][7] = fmaf(a, w1.w, acc[j][7]);
                }
            }
            __syncthreads();
        }
    }
    // epilogue: bias + activation + store + (optional) fused BN partial sums
    float bl[8];
    #pragma unroll
    for (int c = 0; c < 4; c++) {
        bl[c] = bias[cg * 4 + c];
        bl[4 + c] = bias[64 + cg * 4 + c];
    }
    float ps[8], pq[8];
    #pragma unroll
    for (int c = 0; c < 8; c++) { ps[c] = 0.f; pq[c] = 0.f; }
    #pragma unroll
    for (int j = 0; j < 4; j++) {
        int row = row0 + rg + 16 * j;
        if (row < NN) {
            float v[8];
            #pragma unroll
            for (int c = 0; c < 8; c++) {
                float x = acc[j][c] + bl[c];
                if (act == 1) x = x > 0.f ? x : 0.01f * x;
                else if (act == 2) x = x > 0.f ? x : 0.f;
                v[c] = x;
                ps[c] += x;
                pq[c] += x * x;
            }
            *(float4*)(out + row * HD + cg * 4) = make_float4(v[0], v[1], v[2], v[3]);
            *(float4*)(out + row * HD + cg * 4 + 64) = make_float4(v[4], v[5], v[6], v[7]);
        }
    }
    if (gsum) {
        // reuse smem (all LDS reads finished; last loop iter ended in barrier)
        float (*red)[128] = (float(*)[128])smem;
        #pragma unroll
        for (int c = 0; c < 4; c++) {
            red[rg][cg * 4 + c] = ps[c];
            red[rg][64 + cg * 4 + c] = ps[4 + c];
        }
        __syncthreads();
        if (t < 128) {
            float s = 0.f;
            #pragma unroll
            for (int r = 0; r < 16; r++) s += red[r][t];
            atomicAdd(&gsum[t], s);
        }
        __syncthreads();
        #pragma unroll
        for (int c = 0; c < 4; c++) {
            red[rg][cg * 4 + c] = pq[c];
            red[rg][64 + cg * 4 + c] = pq[4 + c];
        }
        __syncthreads();
        if (t < 128) {
            float s = 0.f;
            #pragma unroll
            for (int r = 0; r < 16; r++) s += red[r][t];
            atomicAdd(&gsum[128 + t], s);
        }
    }
}

// ---------------------------------------------------------------------------
// BatchNorm (standalone stats only needed for layer 1)
// ---------------------------------------------------------------------------
__global__ __launch_bounds__(256) void k_bnstats(const float* __restrict__ h,
                                                 float* __restrict__ sums) {
    int f = threadIdx.x & 127;
    int r0 = blockIdx.x * 2 + (threadIdx.x >> 7);
    float s = 0.f, sq = 0.f;
    for (int r = r0; r < NN; r += 2048) {
        float v = h[r * HD + f];
        s += v;
        sq += v * v;
    }
    atomicAdd(&sums[f], s);
    atomicAdd(&sums[HD + f], sq);
}

__global__ __launch_bounds__(128) void k_bnfin(const float* __restrict__ sums,
                                               const float* __restrict__ g,
                                               const float* __restrict__ be,
                                               float* __restrict__ ss) {
    int f = threadIdx.x;
    float mean = sums[f] * (1.0f / NN);
    float var = sums[HD + f] * (1.0f / NN) - mean * mean;
    float sc = g[f] * rsqrtf(var + 1e-5f);
    ss[f] = sc;
    ss[HD + f] = be[f] - mean * sc;
}

__global__ void k_bnapply(float* __restrict__ h, const float* __restrict__ ss) {
    int idx = blockIdx.x * 256 + threadIdx.x;  // over NN*32 float4s
    if (idx < NN * 32) {
        int c4 = idx & 31;
        float4 v = ((float4*)h)[idx];
        float4 sc = ((const float4*)ss)[c4];
        float4 sh = ((const float4*)(ss + HD))[c4];
        v.x = fmaf(v.x, sc.x, sh.x);
        v.y = fmaf(v.y, sc.y, sh.y);
        v.z = fmaf(v.z, sc.z, sh.z);
        v.w = fmaf(v.w, sc.w, sh.w);
        ((float4*)h)[idx] = v;
    }
}

// ---------------------------------------------------------------------------
// Row L2 normalize -> d_out
// ---------------------------------------------------------------------------
__global__ __launch_bounds__(256) void k_l2norm(const float* __restrict__ h,
                                                float* __restrict__ out) {
    int row = blockIdx.x * 4 + (threadIdx.x >> 6);
    int lane = threadIdx.x & 63;
    if (row >= NN) return;
    float2 v = *(const float2*)(h + row * HD + lane * 2);
    float s = v.x * v.x + v.y * v.y;
    #pragma unroll
    for (int off = 32; off > 0; off >>= 1) s += __shfl_xor(s, off);
    float scale = 1.f / fmaxf(sqrtf(s), 1e-12f);
    *(float2*)(out + row * HD + lane * 2) = make_float2(v.x * scale, v.y * scale);
}

// ---------------------------------------------------------------------------
// Launch
// ---------------------------------------------------------------------------
extern "C" void kernel_launch(void* const* d_in, const int* in_sizes, int n_in,
                              void* d_out, int out_size, void* d_ws, size_t ws_size,
                              hipStream_t stream) {
    const float* x  = (const float*)d_in[0];
    const int*   ei = (const int*)d_in[1];
    const float* W1 = (const float*)d_in[2];
    const float* b1 = (const float*)d_in[3];
    const float* W2 = (const float*)d_in[4];
    const float* b2 = (const float*)d_in[5];
    const float* W3 = (const float*)d_in[6];
    const float* b3 = (const float*)d_in[7];
    const float* W4 = (const float*)d_in[8];
    const float* b4 = (const float*)d_in[9];
    const float* g1 = (const float*)d_in[10];
    const float* be1 = (const float*)d_in[11];
    const float* g2 = (const float*)d_in[12];
    const float* be2 = (const float*)d_in[13];
    const float* g3 = (const float*)d_in[14];
    const float* be3 = (const float*)d_in[15];
    float* outp = (float*)d_out;

    // workspace layout (256B aligned slabs)
    char* base = (char*)d_ws;
    size_t off = 0;
    auto alloc = [&](size_t bytes) -> void* {
        void* p = base + off;
        off += (bytes + 255) & ~(size_t)255;
        return p;
    };
    float* deg   = (float*)alloc(NN * 4);
    int*   cnt   = (int*)  alloc(NN * 4);
    int*   fil   = (int*)  alloc(NN * 4);
    float* dinv  = (float*)alloc(NN * 4);
    int*   rowptr= (int*)  alloc((NN + 1) * 4);
    int*   bsum  = (int*)  alloc(64 * 4);
    int*   boff  = (int*)  alloc(64 * 4);
    float* bnsum = (float*)alloc(256 * 4);
    float* ss    = (float*)alloc(256 * 4);
    int2*  edg   = (int2*) alloc((size_t)NE * 8);
    float* T3a   = (float*)alloc(NN * 3 * 4);
    float* T3b   = (float*)alloc(NN * 3 * 4);
    float* T3c   = (float*)alloc(NN * 3 * 4);
    float* B0    = (float*)alloc((size_t)NN * HD * 4);
    float* B1    = (float*)alloc((size_t)NN * HD * 4);
    float* B2    = (float*)alloc((size_t)NN * HD * 4);
    float* B3    = (float*)alloc((size_t)NN * HD * 4);
    float* B4    = (float*)alloc((size_t)NN * HD * 4);

    const int gE = (NE + 255) / 256;     // 3125
    const int gN = (NN + 255) / 256;     // 196
    const int nb = (NN + 1023) / 1024;   // 49

    // ---- graph prep ----
    hipMemsetAsync(deg, 0, ((size_t)(char*)dinv - (size_t)(char*)deg), stream); // deg,cnt,fil
    k_count<<<gE, 256, 0, stream>>>(ei, deg, cnt);
    k_dinv<<<gN, 256, 0, stream>>>(deg, dinv);
    k_scan1<<<nb, 1024, 0, stream>>>(cnt, rowptr, bsum);
    k_scan2<<<1, 64, 0, stream>>>(bsum, boff, nb, rowptr);
    k_scan3<<<gN, 256, 0, stream>>>(rowptr, boff);
    k_fill<<<gE, 256, 0, stream>>>(ei, dinv, rowptr, fil, edg);

    const int gP = NN / 8;                // 6250 blocks, 8 nodes each
    const int gG = (NN + 63) / 64;        // 782
    const int gApply = (NN * 32 + 255) / 256;
    const int gL2 = (NN + 3) / 4;

    // ---- layer 1 (in: x [N,3]) ----
    k_prop3<<<gN, 256, 0, stream>>>(x, nullptr, rowptr, edg, T3a);
    k_prop3<<<gN, 256, 0, stream>>>(T3a, x, rowptr, edg, T3b);
    k_prop3<<<gN, 256, 0, stream>>>(T3b, T3a, rowptr, edg, T3c);
    k_gemm1<<<(NN * 128 + 255) / 256, 256, 0, stream>>>(x, T3a, T3b, T3c, W1, b1, B0);
    hipMemsetAsync(bnsum, 0, 256 * 4, stream);
    k_bnstats<<<1024, 256, 0, stream>>>(B0, bnsum);
    k_bnfin<<<1, 128, 0, stream>>>(bnsum, g1, be1, ss);
    k_bnapply<<<gApply, 256, 0, stream>>>(B0, ss);

    // ---- layer 2 (in: B0) ----
    k_prop128<<<gP, 256, 0, stream>>>(B0, nullptr, rowptr, edg, B1);
    k_prop128<<<gP, 256, 0, stream>>>(B1, B0, rowptr, edg, B2);
    k_prop128<<<gP, 256, 0, stream>>>(B2, B1, rowptr, edg, B3);
    hipMemsetAsync(bnsum, 0, 256 * 4, stream);
    k_gemm128<<<gG, 256, 0, stream>>>(B0, B1, B2, B3, W2, b2, B4, 1, bnsum);
    k_bnfin<<<1, 128, 0, stream>>>(bnsum, g2, be2, ss);
    k_bnapply<<<gApply, 256, 0, stream>>>(B4, ss);

    // ---- layer 3 (in: B4) ----
    k_prop128<<<gP, 256, 0, stream>>>(B4, nullptr, rowptr, edg, B0);
    k_prop128<<<gP, 256, 0, stream>>>(B0, B4, rowptr, edg, B1);
    k_prop128<<<gP, 256, 0, stream>>>(B1, B0, rowptr, edg, B2);
    hipMemsetAsync(bnsum, 0, 256 * 4, stream);
    k_gemm128<<<gG, 256, 0, stream>>>(B4, B0, B1, B2, W3, b3, B3, 2, bnsum);
    k_bnfin<<<1, 128, 0, stream>>>(bnsum, g3, be3, ss);
    k_bnapply<<<gApply, 256, 0, stream>>>(B3, ss);

    // ---- layer 4 (in: B3) ----
    k_prop128<<<gP, 256, 0, stream>>>(B3, nullptr, rowptr, edg, B4);
    k_prop128<<<gP, 256, 0, stream>>>(B4, B3, rowptr, edg, B0);
    k_prop128<<<gP, 256, 0, stream>>>(B0, B4, rowptr, edg, B1);
    k_gemm128<<<gG, 256, 0, stream>>>(B3, B4, B0, B1, W4, b4, B2, 0, nullptr);
    k_l2norm<<<gL2, 256, 0, stream>>>(B2, outp);

    (void)n_in; (void)in_sizes; (void)out_size; (void)ws_size;
}

// Round 3
// 818.653 us; speedup vs baseline: 1.9981x; 1.4965x over previous
//
#include <hip/hip_runtime.h>

#define NN 50000
#define NE 800000
#define HD 128

typedef __attribute__((ext_vector_type(8))) short short8;
typedef __attribute__((ext_vector_type(4))) float f32x4;

__device__ inline unsigned bf2pack(float lo, float hi) {
    unsigned a = __float_as_uint(lo); a = (a + 0x7fffu + ((a >> 16) & 1u)) >> 16;
    unsigned b = __float_as_uint(hi); b = (b + 0x7fffu + ((b >> 16) & 1u)) >> 16;
    return a | (b << 16);
}

// ---------------------------------------------------------------------------
// Graph prep
// ---------------------------------------------------------------------------
__global__ void k_count(const int* __restrict__ ei, float* __restrict__ deg,
                        int* __restrict__ cnt) {
    int e = blockIdx.x * 256 + threadIdx.x;
    if (e < NE) {
        atomicAdd(&deg[ei[e]], 1.0f);
        atomicAdd(&cnt[ei[NE + e]], 1);
    }
}

__global__ void k_dinv(const float* __restrict__ deg, float* __restrict__ dinv) {
    int n = blockIdx.x * 256 + threadIdx.x;
    if (n < NN) {
        float d = deg[n];
        dinv[n] = d > 0.0f ? rsqrtf(d) : 0.0f;
    }
}

__global__ __launch_bounds__(1024) void k_scan1(const int* __restrict__ cnt,
                                                int* __restrict__ rowptr,
                                                int* __restrict__ bsum) {
    __shared__ int s[1024];
    int tid = threadIdx.x;
    int gid = blockIdx.x * 1024 + tid;
    int v = (gid < NN) ? cnt[gid] : 0;
    s[tid] = v;
    __syncthreads();
    for (int off = 1; off < 1024; off <<= 1) {
        int t = 0;
        if (tid >= off) t = s[tid - off];
        __syncthreads();
        s[tid] += t;
        __syncthreads();
    }
    if (gid < NN) rowptr[gid] = s[tid] - v;
    if (tid == 1023) bsum[blockIdx.x] = s[1023];
}

__global__ void k_scan2(const int* __restrict__ bsum, int* __restrict__ boff,
                        int nb, int* __restrict__ rowptr) {
    if (threadIdx.x == 0 && blockIdx.x == 0) {
        int acc = 0;
        for (int i = 0; i < nb; i++) { boff[i] = acc; acc += bsum[i]; }
        rowptr[NN] = acc;
    }
}

__global__ void k_scan3(int* __restrict__ rowptr, const int* __restrict__ boff) {
    int i = blockIdx.x * 256 + threadIdx.x;
    if (i < NN) rowptr[i] += boff[i >> 10];
}

__global__ void k_fill(const int* __restrict__ ei, const float* __restrict__ dinv,
                       const int* __restrict__ rowptr, int* __restrict__ fill,
                       int2* __restrict__ edg) {
    int e = blockIdx.x * 256 + threadIdx.x;
    if (e < NE) {
        int s = ei[e];
        int d = ei[NE + e];
        int pos = rowptr[d] + atomicAdd(&fill[d], 1);
        edg[pos] = make_int2(s, __float_as_int(-dinv[s] * dinv[d]));
    }
}

// ---------------------------------------------------------------------------
// Propagation dim-3 (fp32, layer 1 only)
// ---------------------------------------------------------------------------
__global__ void k_prop3(const float* __restrict__ h, const float* __restrict__ sub,
                        const int* __restrict__ rowptr, const int2* __restrict__ edg,
                        float* __restrict__ out) {
    int node = blockIdx.x * 256 + threadIdx.x;
    if (node >= NN) return;
    int e0 = rowptr[node], e1 = rowptr[node + 1];
    float a0 = 0.f, a1 = 0.f, a2 = 0.f;
    for (int e = e0; e < e1; e++) {
        int2 p = edg[e];
        int s = p.x;
        float v = __int_as_float(p.y);
        a0 += v * h[s * 3 + 0];
        a1 += v * h[s * 3 + 1];
        a2 += v * h[s * 3 + 2];
    }
    if (sub) {
        a0 = 2.f * a0 - sub[node * 3 + 0];
        a1 = 2.f * a1 - sub[node * 3 + 1];
        a2 = 2.f * a2 - sub[node * 3 + 2];
    }
    out[node * 3 + 0] = a0;
    out[node * 3 + 1] = a1;
    out[node * 3 + 2] = a2;
}

// ---------------------------------------------------------------------------
// Propagation dim-128, bf16 storage, fp32 accumulate.
// 16 lanes/node (8 features each, ushort8=16B loads), 16 nodes/block.
// ---------------------------------------------------------------------------
#define ACC8(acc, u, v)                                             \
    acc[0] = fmaf(v, __uint_as_float(u.x << 16), acc[0]);           \
    acc[1] = fmaf(v, __uint_as_float(u.x & 0xffff0000u), acc[1]);   \
    acc[2] = fmaf(v, __uint_as_float(u.y << 16), acc[2]);           \
    acc[3] = fmaf(v, __uint_as_float(u.y & 0xffff0000u), acc[3]);   \
    acc[4] = fmaf(v, __uint_as_float(u.z << 16), acc[4]);           \
    acc[5] = fmaf(v, __uint_as_float(u.z & 0xffff0000u), acc[5]);   \
    acc[6] = fmaf(v, __uint_as_float(u.w << 16), acc[6]);           \
    acc[7] = fmaf(v, __uint_as_float(u.w & 0xffff0000u), acc[7]);

__global__ __launch_bounds__(256) void k_prop_bf(
        const unsigned short* __restrict__ h, const unsigned short* __restrict__ sub,
        const int* __restrict__ rowptr, const int2* __restrict__ edg,
        unsigned short* __restrict__ out) {
    int node = blockIdx.x * 16 + (threadIdx.x >> 4);
    int f8 = (threadIdx.x & 15) * 8;
    int e0 = rowptr[node], e1 = rowptr[node + 1];
    float a[8] = {0, 0, 0, 0, 0, 0, 0, 0};
    float b[8] = {0, 0, 0, 0, 0, 0, 0, 0};
    int e = e0;
    for (; e + 4 <= e1; e += 4) {
        int2 p0 = edg[e];
        int2 p1 = edg[e + 1];
        int2 p2 = edg[e + 2];
        int2 p3 = edg[e + 3];
        uint4 u0 = *(const uint4*)(h + p0.x * HD + f8);
        uint4 u1 = *(const uint4*)(h + p1.x * HD + f8);
        uint4 u2 = *(const uint4*)(h + p2.x * HD + f8);
        uint4 u3 = *(const uint4*)(h + p3.x * HD + f8);
        float v0 = __int_as_float(p0.y);
        float v1 = __int_as_float(p1.y);
        float v2 = __int_as_float(p2.y);
        float v3 = __int_as_float(p3.y);
        ACC8(a, u0, v0)
        ACC8(b, u1, v1)
        ACC8(a, u2, v2)
        ACC8(b, u3, v3)
    }
    for (; e < e1; e++) {
        int2 p = edg[e];
        uint4 u = *(const uint4*)(h + p.x * HD + f8);
        float v = __int_as_float(p.y);
        ACC8(a, u, v)
    }
    float r[8];
    #pragma unroll
    for (int j = 0; j < 8; j++) r[j] = a[j] + b[j];
    if (sub) {
        uint4 su = *(const uint4*)(sub + node * HD + f8);
        float s[8];
        s[0] = __uint_as_float(su.x << 16); s[1] = __uint_as_float(su.x & 0xffff0000u);
        s[2] = __uint_as_float(su.y << 16); s[3] = __uint_as_float(su.y & 0xffff0000u);
        s[4] = __uint_as_float(su.z << 16); s[5] = __uint_as_float(su.z & 0xffff0000u);
        s[6] = __uint_as_float(su.w << 16); s[7] = __uint_as_float(su.w & 0xffff0000u);
        #pragma unroll
        for (int j = 0; j < 8; j++) r[j] = 2.f * r[j] - s[j];
    }
    uint4 o;
    o.x = bf2pack(r[0], r[1]);
    o.y = bf2pack(r[2], r[3]);
    o.z = bf2pack(r[4], r[5]);
    o.w = bf2pack(r[6], r[7]);
    *(uint4*)(out + node * HD + f8) = o;
}

// ---------------------------------------------------------------------------
// W swizzle fp32 -> bf16 B-fragment order for mfma_f32_16x16x32_bf16.
// Wb[slot=(w*2+g)*16+t][lane][j] = W[k=t*32+(lane>>4)*8+j][col=w*32+g*16+(lane&15)]
// ---------------------------------------------------------------------------
__global__ void k_wconv(const float* __restrict__ W, unsigned short* __restrict__ Wb) {
    int idx = blockIdx.x * 256 + threadIdx.x;  // 0..65535
    int slot = idx >> 9;
    int lane = (idx >> 3) & 63;
    int j = idx & 7;
    int wg = slot >> 4;
    int t = slot & 15;
    int w = wg >> 1;
    int g = wg & 1;
    int k = t * 32 + (lane >> 4) * 8 + j;
    int col = w * 32 + g * 16 + (lane & 15);
    unsigned u = __float_as_uint(W[k * HD + col]);
    Wb[idx] = (unsigned short)((u + 0x7fffu + ((u >> 16) & 1u)) >> 16);
}

// ---------------------------------------------------------------------------
// MFMA GEMM: out[n,f] = act( b[f] + sum_{k<512} A[n,k] * W[k,f] )
// A = 4 bf16 Tx buffers (k-blocks of 128). 4 waves/block, wave w owns cols
// [32w,32w+32). B register-resident (128 VGPR). Grid-stride over 16-row tiles.
// outF fp32 (act applied). Optional fused BN column sums -> gsum[256].
// ---------------------------------------------------------------------------
__global__ __launch_bounds__(256) void k_gemmM(
        const unsigned short* __restrict__ A0, const unsigned short* __restrict__ A1,
        const unsigned short* __restrict__ A2, const unsigned short* __restrict__ A3,
        const unsigned short* __restrict__ Wb, const float* __restrict__ bias,
        float* __restrict__ outF, int act, float* __restrict__ gsum) {
    const int tid = threadIdx.x;
    const int w = tid >> 6;
    const int lane = tid & 63;
    const int l15 = lane & 15;
    const int quad = lane >> 4;

    // load B fragments (held in registers for the whole kernel)
    short8 Bf[16][2];
    #pragma unroll
    for (int t = 0; t < 16; t++) {
        #pragma unroll
        for (int g = 0; g < 2; g++) {
            int slot = (w * 2 + g) * 16 + t;
            Bf[t][g] = *(const short8*)(Wb + slot * 512 + lane * 8);
        }
    }
    float bcol[2];
    bcol[0] = bias[w * 32 + l15];
    bcol[1] = bias[w * 32 + 16 + l15];

    const unsigned short* Ap[4] = {A0, A1, A2, A3};
    float bnP[2] = {0.f, 0.f}, bnQ[2] = {0.f, 0.f};

    for (int tile = blockIdx.x; tile < NN / 16; tile += gridDim.x) {
        int r0 = tile * 16;
        f32x4 acc0 = {0.f, 0.f, 0.f, 0.f};
        f32x4 acc1 = {0.f, 0.f, 0.f, 0.f};
        #pragma unroll
        for (int t = 0; t < 16; t++) {
            const unsigned short* A = Ap[t >> 2];
            short8 af = *(const short8*)(A + (r0 + l15) * HD + (t & 3) * 32 + quad * 8);
            acc0 = __builtin_amdgcn_mfma_f32_16x16x32_bf16(af, Bf[t][0], acc0, 0, 0, 0);
            acc1 = __builtin_amdgcn_mfma_f32_16x16x32_bf16(af, Bf[t][1], acc1, 0, 0, 0);
        }
        // epilogue: C[row=quad*4+reg][col=w*32+g*16+l15]
        #pragma unroll
        for (int reg = 0; reg < 4; reg++) {
            int row = r0 + quad * 4 + reg;
            float v0 = acc0[reg] + bcol[0];
            float v1 = acc1[reg] + bcol[1];
            if (act == 1) {
                v0 = v0 > 0.f ? v0 : 0.01f * v0;
                v1 = v1 > 0.f ? v1 : 0.01f * v1;
            } else if (act == 2) {
                v0 = v0 > 0.f ? v0 : 0.f;
                v1 = v1 > 0.f ? v1 : 0.f;
            }
            outF[row * HD + w * 32 + l15] = v0;
            outF[row * HD + w * 32 + 16 + l15] = v1;
            bnP[0] += v0; bnQ[0] += v0 * v0;
            bnP[1] += v1; bnQ[1] += v1 * v1;
        }
    }
    if (gsum) {
        #pragma unroll
        for (int g = 0; g < 2; g++) {
            float p = bnP[g], q = bnQ[g];
            p += __shfl_xor(p, 16); p += __shfl_xor(p, 32);
            q += __shfl_xor(q, 16); q += __shfl_xor(q, 32);
            if (quad == 0) {
                int col = w * 32 + g * 16 + l15;
                atomicAdd(&gsum[col], p);
                atomicAdd(&gsum[128 + col], q);
            }
        }
    }
}

// ---------------------------------------------------------------------------
// Layer-1 GEMM: [N,3] x4 Cheb terms @ W1[4][3][128] + b, leaky relu -> fp32
// ---------------------------------------------------------------------------
__global__ __launch_bounds__(256) void k_gemm1(
        const float* __restrict__ T0, const float* __restrict__ T1,
        const float* __restrict__ T2, const float* __restrict__ T3,
        const float* __restrict__ W, const float* __restrict__ bias,
        float* __restrict__ out) {
    __shared__ float Ws[12 * 128];
    __shared__ float tx[2][12];
    int t = threadIdx.x;
    for (int i = t; i < 12 * 128; i += 256) Ws[i] = W[i];
    int idx = blockIdx.x * 256 + t;
    int node = idx >> 7;
    int f = idx & 127;
    int localn = t >> 7;
    const float* Ts[4] = {T0, T1, T2, T3};
    if (f < 12 && node < NN) {
        tx[localn][f] = Ts[f / 3][node * 3 + (f % 3)];
    }
    __syncthreads();
    if (node < NN) {
        float acc = bias[f];
        #pragma unroll
        for (int c = 0; c < 12; c++) acc = fmaf(tx[localn][c], Ws[c * 128 + f], acc);
        acc = acc > 0.f ? acc : 0.01f * acc;
        out[node * HD + f] = acc;
    }
}

// ---------------------------------------------------------------------------
// BatchNorm
// ---------------------------------------------------------------------------
__global__ __launch_bounds__(256) void k_bnstats(const float* __restrict__ h,
                                                 float* __restrict__ sums) {
    int f = threadIdx.x & 127;
    int r0 = blockIdx.x * 2 + (threadIdx.x >> 7);
    float s = 0.f, sq = 0.f;
    for (int r = r0; r < NN; r += 2048) {
        float v = h[r * HD + f];
        s += v;
        sq += v * v;
    }
    atomicAdd(&sums[f], s);
    atomicAdd(&sums[HD + f], sq);
}

__global__ __launch_bounds__(128) void k_bnfin(const float* __restrict__ sums,
                                               const float* __restrict__ g,
                                               const float* __restrict__ be,
                                               float* __restrict__ ss) {
    int f = threadIdx.x;
    float mean = sums[f] * (1.0f / NN);
    float var = sums[HD + f] * (1.0f / NN) - mean * mean;
    float sc = g[f] * rsqrtf(var + 1e-5f);
    ss[f] = sc;
    ss[HD + f] = be[f] - mean * sc;
}

// apply BN to fp32 src, emit bf16
__global__ void k_bnapply_cvt(const float* __restrict__ h, const float* __restrict__ ss,
                              unsigned short* __restrict__ out) {
    int idx = blockIdx.x * 256 + threadIdx.x;  // over NN*32 float4s
    if (idx < NN * 32) {
        int c4 = idx & 31;
        float4 v = ((const float4*)h)[idx];
        float4 sc = ((const float4*)ss)[c4];
        float4 sh = ((const float4*)(ss + HD))[c4];
        v.x = fmaf(v.x, sc.x, sh.x);
        v.y = fmaf(v.y, sc.y, sh.y);
        v.z = fmaf(v.z, sc.z, sh.z);
        v.w = fmaf(v.w, sc.w, sh.w);
        uint2 o;
        o.x = bf2pack(v.x, v.y);
        o.y = bf2pack(v.z, v.w);
        ((uint2*)out)[idx] = o;
    }
}

// ---------------------------------------------------------------------------
// Row L2 normalize -> d_out (fp32 in, fp32 out)
// ---------------------------------------------------------------------------
__global__ __launch_bounds__(256) void k_l2norm(const float* __restrict__ h,
                                                float* __restrict__ out) {
    int row = blockIdx.x * 4 + (threadIdx.x >> 6);
    int lane = threadIdx.x & 63;
    if (row >= NN) return;
    float2 v = *(const float2*)(h + row * HD + lane * 2);
    float s = v.x * v.x + v.y * v.y;
    #pragma unroll
    for (int off = 32; off > 0; off >>= 1) s += __shfl_xor(s, off);
    float scale = 1.f / fmaxf(sqrtf(s), 1e-12f);
    *(float2*)(out + row * HD + lane * 2) = make_float2(v.x * scale, v.y * scale);
}

// ---------------------------------------------------------------------------
// Launch
// ---------------------------------------------------------------------------
extern "C" void kernel_launch(void* const* d_in, const int* in_sizes, int n_in,
                              void* d_out, int out_size, void* d_ws, size_t ws_size,
                              hipStream_t stream) {
    const float* x  = (const float*)d_in[0];
    const int*   ei = (const int*)d_in[1];
    const float* W1 = (const float*)d_in[2];
    const float* b1 = (const float*)d_in[3];
    const float* W2 = (const float*)d_in[4];
    const float* b2 = (const float*)d_in[5];
    const float* W3 = (const float*)d_in[6];
    const float* b3 = (const float*)d_in[7];
    const float* W4 = (const float*)d_in[8];
    const float* b4 = (const float*)d_in[9];
    const float* g1 = (const float*)d_in[10];
    const float* be1 = (const float*)d_in[11];
    const float* g2 = (const float*)d_in[12];
    const float* be2 = (const float*)d_in[13];
    const float* g3 = (const float*)d_in[14];
    const float* be3 = (const float*)d_in[15];
    float* outp = (float*)d_out;

    char* base = (char*)d_ws;
    size_t off = 0;
    auto alloc = [&](size_t bytes) -> void* {
        void* p = base + off;
        off += (bytes + 255) & ~(size_t)255;
        return p;
    };
    float* deg   = (float*)alloc(NN * 4);
    int*   cnt   = (int*)  alloc(NN * 4);
    int*   fil   = (int*)  alloc(NN * 4);
    float* dinv  = (float*)alloc(NN * 4);
    int*   rowptr= (int*)  alloc((NN + 1) * 4);
    int*   bsum  = (int*)  alloc(64 * 4);
    int*   boff  = (int*)  alloc(64 * 4);
    float* bnsum = (float*)alloc(256 * 4);
    float* ss    = (float*)alloc(256 * 4);
    unsigned short* Wb = (unsigned short*)alloc(512 * 128 * 2);
    int2*  edg   = (int2*) alloc((size_t)NE * 8);
    float* T3a   = (float*)alloc(NN * 3 * 4);
    float* T3b   = (float*)alloc(NN * 3 * 4);
    float* T3c   = (float*)alloc(NN * 3 * 4);
    float* F0    = (float*)alloc((size_t)NN * HD * 4);
    unsigned short* Bb0 = (unsigned short*)alloc((size_t)NN * HD * 2);
    unsigned short* Bb1 = (unsigned short*)alloc((size_t)NN * HD * 2);
    unsigned short* Bb2 = (unsigned short*)alloc((size_t)NN * HD * 2);
    unsigned short* Bb3 = (unsigned short*)alloc((size_t)NN * HD * 2);

    const int gE = (NE + 255) / 256;
    const int gN = (NN + 255) / 256;
    const int nb = (NN + 1023) / 1024;

    // ---- graph prep ----
    hipMemsetAsync(deg, 0, ((size_t)(char*)dinv - (size_t)(char*)deg), stream);
    k_count<<<gE, 256, 0, stream>>>(ei, deg, cnt);
    k_dinv<<<gN, 256, 0, stream>>>(deg, dinv);
    k_scan1<<<nb, 1024, 0, stream>>>(cnt, rowptr, bsum);
    k_scan2<<<1, 64, 0, stream>>>(bsum, boff, nb, rowptr);
    k_scan3<<<gN, 256, 0, stream>>>(rowptr, boff);
    k_fill<<<gE, 256, 0, stream>>>(ei, dinv, rowptr, fil, edg);

    const int gP = NN / 16;               // 3125, 16 nodes/block
    const int gG = 625;                   // gemmM grid-stride blocks
    const int gApply = (NN * 32 + 255) / 256;
    const int gL2 = (NN + 3) / 4;

    // ---- layer 1 (in: x [N,3], fp32) ----
    k_prop3<<<gN, 256, 0, stream>>>(x, nullptr, rowptr, edg, T3a);
    k_prop3<<<gN, 256, 0, stream>>>(T3a, x, rowptr, edg, T3b);
    k_prop3<<<gN, 256, 0, stream>>>(T3b, T3a, rowptr, edg, T3c);
    k_gemm1<<<(NN * 128 + 255) / 256, 256, 0, stream>>>(x, T3a, T3b, T3c, W1, b1, F0);
    hipMemsetAsync(bnsum, 0, 256 * 4, stream);
    k_bnstats<<<1024, 256, 0, stream>>>(F0, bnsum);
    k_bnfin<<<1, 128, 0, stream>>>(bnsum, g1, be1, ss);
    k_bnapply_cvt<<<gApply, 256, 0, stream>>>(F0, ss, Bb0);

    // ---- layer 2 ----
    k_wconv<<<256, 256, 0, stream>>>(W2, Wb);
    k_prop_bf<<<gP, 256, 0, stream>>>(Bb0, nullptr, rowptr, edg, Bb1);
    k_prop_bf<<<gP, 256, 0, stream>>>(Bb1, Bb0, rowptr, edg, Bb2);
    k_prop_bf<<<gP, 256, 0, stream>>>(Bb2, Bb1, rowptr, edg, Bb3);
    hipMemsetAsync(bnsum, 0, 256 * 4, stream);
    k_gemmM<<<gG, 256, 0, stream>>>(Bb0, Bb1, Bb2, Bb3, Wb, b2, F0, 1, bnsum);
    k_bnfin<<<1, 128, 0, stream>>>(bnsum, g2, be2, ss);
    k_bnapply_cvt<<<gApply, 256, 0, stream>>>(F0, ss, Bb0);

    // ---- layer 3 ----
    k_wconv<<<256, 256, 0, stream>>>(W3, Wb);
    k_prop_bf<<<gP, 256, 0, stream>>>(Bb0, nullptr, rowptr, edg, Bb1);
    k_prop_bf<<<gP, 256, 0, stream>>>(Bb1, Bb0, rowptr, edg, Bb2);
    k_prop_bf<<<gP, 256, 0, stream>>>(Bb2, Bb1, rowptr, edg, Bb3);
    hipMemsetAsync(bnsum, 0, 256 * 4, stream);
    k_gemmM<<<gG, 256, 0, stream>>>(Bb0, Bb1, Bb2, Bb3, Wb, b3, F0, 2, bnsum);
    k_bnfin<<<1, 128, 0, stream>>>(bnsum, g3, be3, ss);
    k_bnapply_cvt<<<gApply, 256, 0, stream>>>(F0, ss, Bb0);

    // ---- layer 4 ----
    k_wconv<<<256, 256, 0, stream>>>(W4, Wb);
    k_prop_bf<<<gP, 256, 0, stream>>>(Bb0, nullptr, rowptr, edg, Bb1);
    k_prop_bf<<<gP, 256, 0, stream>>>(Bb1, Bb0, rowptr, edg, Bb2);
    k_prop_bf<<<gP, 256, 0, stream>>>(Bb2, Bb1, rowptr, edg, Bb3);
    k_gemmM<<<gG, 256, 0, stream>>>(Bb0, Bb1, Bb2, Bb3, Wb, b4, F0, 0, nullptr);
    k_l2norm<<<gL2, 256, 0, stream>>>(F0, outp);

    (void)n_in; (void)in_sizes; (void)out_size; (void)ws_size;
}

// Round 4
// 764.570 us; speedup vs baseline: 2.1394x; 1.0707x over previous
//
#include <hip/hip_runtime.h>

#define NN 50000
#define NE 800000
#define HD 128
#define NSL 128          // edge slices
#define SLE (NE / NSL)   // 6250 edges per slice
#define PW  12500        // packed words per chunk (2 bins/word, 25000 bins/chunk)

typedef __attribute__((ext_vector_type(8))) short short8;
typedef __attribute__((ext_vector_type(4))) float f32x4;

__device__ inline unsigned bf2pack(float lo, float hi) {
    unsigned a = __float_as_uint(lo); a = (a + 0x7fffu + ((a >> 16) & 1u)) >> 16;
    unsigned b = __float_as_uint(hi); b = (b + 0x7fffu + ((b >> 16) & 1u)) >> 16;
    return a | (b << 16);
}

// ---------------------------------------------------------------------------
// Graph prep, atomic-free:
// k_hist: per-(array, slice, chunk) LDS histogram (packed u16 pairs), flushed
// non-atomically to phist. 512 blocks.
// ---------------------------------------------------------------------------
__global__ __launch_bounds__(256) void k_hist(const int* __restrict__ ei,
                                              unsigned* __restrict__ phist) {
    __shared__ unsigned hist[PW];  // 50 KB
    int b = blockIdx.x;
    int a = b >> 8;          // 0=src, 1=dst
    int s = (b & 255) >> 1;  // slice
    int c = b & 1;           // chunk
    int tid = threadIdx.x;
    for (int i = tid; i < PW; i += 256) hist[i] = 0u;
    __syncthreads();
    const int* arr = ei + a * NE + s * SLE;
    int lo = c * 25000;
    for (int i = tid; i < SLE; i += 256) {
        int v = arr[i] - lo;
        if ((unsigned)v < 25000u)
            atomicAdd(&hist[v >> 1], 1u << ((v & 1) * 16));
    }
    __syncthreads();
    unsigned* dst = phist + (size_t)b * PW;  // b == ((a*NSL+s)*2+c)
    for (int i = tid; i < PW; i += 256) dst[i] = hist[i];
}

// Reduce partials: a=0 -> dinv (rsqrt of src out-degree); a=1 -> cnt + pre[]
__global__ __launch_bounds__(256) void k_hreduce(const unsigned* __restrict__ phist,
                                                 float* __restrict__ dinv,
                                                 int* __restrict__ cnt,
                                                 unsigned* __restrict__ pre) {
    int idx = blockIdx.x * 256 + threadIdx.x;
    if (idx >= 50000) return;
    int a = idx / 25000;
    int gw = idx % 25000;          // global packed-word id
    int c = gw / PW;
    int w = gw % PW;
    unsigned accLo = 0, accHi = 0;
    for (int s = 0; s < NSL; s++) {
        unsigned p = phist[(size_t)(((a * NSL + s) * 2 + c)) * PW + w];
        if (a == 1) pre[(size_t)s * 25000 + gw] = accLo | (accHi << 16);
        accLo += p & 0xffffu;
        accHi += p >> 16;
    }
    int b0 = c * 25000 + 2 * (gw % PW);
    if (a == 0) {
        dinv[b0]     = accLo ? rsqrtf((float)accLo) : 0.0f;
        dinv[b0 + 1] = accHi ? rsqrtf((float)accHi) : 0.0f;
    } else {
        cnt[b0]     = (int)accLo;
        cnt[b0 + 1] = (int)accHi;
    }
}

__global__ __launch_bounds__(1024) void k_scan1(const int* __restrict__ cnt,
                                                int* __restrict__ rowptr,
                                                int* __restrict__ bsum) {
    __shared__ int s[1024];
    int tid = threadIdx.x;
    int gid = blockIdx.x * 1024 + tid;
    int v = (gid < NN) ? cnt[gid] : 0;
    s[tid] = v;
    __syncthreads();
    for (int off = 1; off < 1024; off <<= 1) {
        int t = 0;
        if (tid >= off) t = s[tid - off];
        __syncthreads();
        s[tid] += t;
        __syncthreads();
    }
    if (gid < NN) rowptr[gid] = s[tid] - v;
    if (tid == 1023) bsum[blockIdx.x] = s[1023];
}

__global__ void k_scan2(const int* __restrict__ bsum, int* __restrict__ boff,
                        int nb, int* __restrict__ rowptr) {
    if (threadIdx.x == 0 && blockIdx.x == 0) {
        int acc = 0;
        for (int i = 0; i < nb; i++) { boff[i] = acc; acc += bsum[i]; }
        rowptr[NN] = acc;
    }
}

__global__ void k_scan3(int* __restrict__ rowptr, const int* __restrict__ boff) {
    int i = blockIdx.x * 256 + threadIdx.x;
    if (i < NN) rowptr[i] += boff[i >> 10];
}

// Atomic-free CSR fill: pos = rowptr[d] + pre[slice][d] + LDS-rank-in-slice
__global__ __launch_bounds__(256) void k_fill2(const int* __restrict__ ei,
                                               const float* __restrict__ dinv,
                                               const int* __restrict__ rowptr,
                                               const unsigned* __restrict__ pre,
                                               int2* __restrict__ edg) {
    __shared__ unsigned rank[PW];  // 50 KB
    int b = blockIdx.x;
    int s = b >> 1;
    int c = b & 1;
    int tid = threadIdx.x;
    for (int i = tid; i < PW; i += 256) rank[i] = 0u;
    __syncthreads();
    int lo = c * 25000;
    const unsigned* preS = pre + (size_t)s * 25000 + c * PW;
    for (int i = tid; i < SLE; i += 256) {
        int e = s * SLE + i;
        int d = ei[NE + e];
        int v = d - lo;
        if ((unsigned)v < 25000u) {
            int src = ei[e];
            int w = v >> 1;
            int sh = (v & 1) * 16;
            unsigned r = atomicAdd(&rank[w], 1u << sh);
            r = (r >> sh) & 0xffffu;
            unsigned pw = (preS[w] >> sh) & 0xffffu;
            int pos = rowptr[d] + (int)pw + (int)r;
            edg[pos] = make_int2(src, __float_as_int(-dinv[src] * dinv[d]));
        }
    }
}

// ---------------------------------------------------------------------------
// Propagation dim-3 (fp32, layer 1 only)
// ---------------------------------------------------------------------------
__global__ void k_prop3(const float* __restrict__ h, const float* __restrict__ sub,
                        const int* __restrict__ rowptr, const int2* __restrict__ edg,
                        float* __restrict__ out) {
    int node = blockIdx.x * 256 + threadIdx.x;
    if (node >= NN) return;
    int e0 = rowptr[node], e1 = rowptr[node + 1];
    float a0 = 0.f, a1 = 0.f, a2 = 0.f;
    for (int e = e0; e < e1; e++) {
        int2 p = edg[e];
        int s = p.x;
        float v = __int_as_float(p.y);
        a0 += v * h[s * 3 + 0];
        a1 += v * h[s * 3 + 1];
        a2 += v * h[s * 3 + 2];
    }
    if (sub) {
        a0 = 2.f * a0 - sub[node * 3 + 0];
        a1 = 2.f * a1 - sub[node * 3 + 1];
        a2 = 2.f * a2 - sub[node * 3 + 2];
    }
    out[node * 3 + 0] = a0;
    out[node * 3 + 1] = a1;
    out[node * 3 + 2] = a2;
}

// ---------------------------------------------------------------------------
// Propagation dim-128, bf16 storage, fp32 accumulate.
// 16 lanes/node (8 features each, 16B loads), 16 nodes/block.
// ---------------------------------------------------------------------------
#define ACC8(acc, u, v)                                             \
    acc[0] = fmaf(v, __uint_as_float(u.x << 16), acc[0]);           \
    acc[1] = fmaf(v, __uint_as_float(u.x & 0xffff0000u), acc[1]);   \
    acc[2] = fmaf(v, __uint_as_float(u.y << 16), acc[2]);           \
    acc[3] = fmaf(v, __uint_as_float(u.y & 0xffff0000u), acc[3]);   \
    acc[4] = fmaf(v, __uint_as_float(u.z << 16), acc[4]);           \
    acc[5] = fmaf(v, __uint_as_float(u.z & 0xffff0000u), acc[5]);   \
    acc[6] = fmaf(v, __uint_as_float(u.w << 16), acc[6]);           \
    acc[7] = fmaf(v, __uint_as_float(u.w & 0xffff0000u), acc[7]);

__global__ __launch_bounds__(256) void k_prop_bf(
        const unsigned short* __restrict__ h, const unsigned short* __restrict__ sub,
        const int* __restrict__ rowptr, const int2* __restrict__ edg,
        unsigned short* __restrict__ out) {
    int node = blockIdx.x * 16 + (threadIdx.x >> 4);
    int f8 = (threadIdx.x & 15) * 8;
    int e0 = rowptr[node], e1 = rowptr[node + 1];
    float a[8] = {0, 0, 0, 0, 0, 0, 0, 0};
    float b[8] = {0, 0, 0, 0, 0, 0, 0, 0};
    int e = e0;
    for (; e + 4 <= e1; e += 4) {
        int2 p0 = edg[e];
        int2 p1 = edg[e + 1];
        int2 p2 = edg[e + 2];
        int2 p3 = edg[e + 3];
        uint4 u0 = *(const uint4*)(h + p0.x * HD + f8);
        uint4 u1 = *(const uint4*)(h + p1.x * HD + f8);
        uint4 u2 = *(const uint4*)(h + p2.x * HD + f8);
        uint4 u3 = *(const uint4*)(h + p3.x * HD + f8);
        float v0 = __int_as_float(p0.y);
        float v1 = __int_as_float(p1.y);
        float v2 = __int_as_float(p2.y);
        float v3 = __int_as_float(p3.y);
        ACC8(a, u0, v0)
        ACC8(b, u1, v1)
        ACC8(a, u2, v2)
        ACC8(b, u3, v3)
    }
    for (; e < e1; e++) {
        int2 p = edg[e];
        uint4 u = *(const uint4*)(h + p.x * HD + f8);
        float v = __int_as_float(p.y);
        ACC8(a, u, v)
    }
    float r[8];
    #pragma unroll
    for (int j = 0; j < 8; j++) r[j] = a[j] + b[j];
    if (sub) {
        uint4 su = *(const uint4*)(sub + node * HD + f8);
        float s[8];
        s[0] = __uint_as_float(su.x << 16); s[1] = __uint_as_float(su.x & 0xffff0000u);
        s[2] = __uint_as_float(su.y << 16); s[3] = __uint_as_float(su.y & 0xffff0000u);
        s[4] = __uint_as_float(su.z << 16); s[5] = __uint_as_float(su.z & 0xffff0000u);
        s[6] = __uint_as_float(su.w << 16); s[7] = __uint_as_float(su.w & 0xffff0000u);
        #pragma unroll
        for (int j = 0; j < 8; j++) r[j] = 2.f * r[j] - s[j];
    }
    uint4 o;
    o.x = bf2pack(r[0], r[1]);
    o.y = bf2pack(r[2], r[3]);
    o.z = bf2pack(r[4], r[5]);
    o.w = bf2pack(r[6], r[7]);
    *(uint4*)(out + node * HD + f8) = o;
}

// ---------------------------------------------------------------------------
// W swizzle fp32 -> bf16 B-fragment order for mfma_f32_16x16x32_bf16.
// ---------------------------------------------------------------------------
__global__ void k_wconv(const float* __restrict__ W, unsigned short* __restrict__ Wb) {
    int idx = blockIdx.x * 256 + threadIdx.x;  // 0..65535
    int slot = idx >> 9;
    int lane = (idx >> 3) & 63;
    int j = idx & 7;
    int wg = slot >> 4;
    int t = slot & 15;
    int w = wg >> 1;
    int g = wg & 1;
    int k = t * 32 + (lane >> 4) * 8 + j;
    int col = w * 32 + g * 16 + (lane & 15);
    unsigned u = __float_as_uint(W[k * HD + col]);
    Wb[idx] = (unsigned short)((u + 0x7fffu + ((u >> 16) & 1u)) >> 16);
}

// ---------------------------------------------------------------------------
// MFMA GEMM, B register-resident, fused BN column sums.
// ---------------------------------------------------------------------------
__global__ __launch_bounds__(256) void k_gemmM(
        const unsigned short* __restrict__ A0, const unsigned short* __restrict__ A1,
        const unsigned short* __restrict__ A2, const unsigned short* __restrict__ A3,
        const unsigned short* __restrict__ Wb, const float* __restrict__ bias,
        float* __restrict__ outF, int act, float* __restrict__ gsum) {
    const int tid = threadIdx.x;
    const int w = tid >> 6;
    const int lane = tid & 63;
    const int l15 = lane & 15;
    const int quad = lane >> 4;

    short8 Bf[16][2];
    #pragma unroll
    for (int t = 0; t < 16; t++) {
        #pragma unroll
        for (int g = 0; g < 2; g++) {
            int slot = (w * 2 + g) * 16 + t;
            Bf[t][g] = *(const short8*)(Wb + slot * 512 + lane * 8);
        }
    }
    float bcol[2];
    bcol[0] = bias[w * 32 + l15];
    bcol[1] = bias[w * 32 + 16 + l15];

    const unsigned short* Ap[4] = {A0, A1, A2, A3};
    float bnP[2] = {0.f, 0.f}, bnQ[2] = {0.f, 0.f};

    for (int tile = blockIdx.x; tile < NN / 16; tile += gridDim.x) {
        int r0 = tile * 16;
        f32x4 acc0 = {0.f, 0.f, 0.f, 0.f};
        f32x4 acc1 = {0.f, 0.f, 0.f, 0.f};
        #pragma unroll
        for (int t = 0; t < 16; t++) {
            const unsigned short* A = Ap[t >> 2];
            short8 af = *(const short8*)(A + (r0 + l15) * HD + (t & 3) * 32 + quad * 8);
            acc0 = __builtin_amdgcn_mfma_f32_16x16x32_bf16(af, Bf[t][0], acc0, 0, 0, 0);
            acc1 = __builtin_amdgcn_mfma_f32_16x16x32_bf16(af, Bf[t][1], acc1, 0, 0, 0);
        }
        #pragma unroll
        for (int reg = 0; reg < 4; reg++) {
            int row = r0 + quad * 4 + reg;
            float v0 = acc0[reg] + bcol[0];
            float v1 = acc1[reg] + bcol[1];
            if (act == 1) {
                v0 = v0 > 0.f ? v0 : 0.01f * v0;
                v1 = v1 > 0.f ? v1 : 0.01f * v1;
            } else if (act == 2) {
                v0 = v0 > 0.f ? v0 : 0.f;
                v1 = v1 > 0.f ? v1 : 0.f;
            }
            outF[row * HD + w * 32 + l15] = v0;
            outF[row * HD + w * 32 + 16 + l15] = v1;
            bnP[0] += v0; bnQ[0] += v0 * v0;
            bnP[1] += v1; bnQ[1] += v1 * v1;
        }
    }
    if (gsum) {
        #pragma unroll
        for (int g = 0; g < 2; g++) {
            float p = bnP[g], q = bnQ[g];
            p += __shfl_xor(p, 16); p += __shfl_xor(p, 32);
            q += __shfl_xor(q, 16); q += __shfl_xor(q, 32);
            if (quad == 0) {
                int col = w * 32 + g * 16 + l15;
                atomicAdd(&gsum[col], p);
                atomicAdd(&gsum[128 + col], q);
            }
        }
    }
}

// ---------------------------------------------------------------------------
// Layer-1 GEMM: [N,3] x4 Cheb terms @ W1[4][3][128] + b, leaky relu -> fp32
// ---------------------------------------------------------------------------
__global__ __launch_bounds__(256) void k_gemm1(
        const float* __restrict__ T0, const float* __restrict__ T1,
        const float* __restrict__ T2, const float* __restrict__ T3,
        const float* __restrict__ W, const float* __restrict__ bias,
        float* __restrict__ out) {
    __shared__ float Ws[12 * 128];
    __shared__ float tx[2][12];
    int t = threadIdx.x;
    for (int i = t; i < 12 * 128; i += 256) Ws[i] = W[i];
    int idx = blockIdx.x * 256 + t;
    int node = idx >> 7;
    int f = idx & 127;
    int localn = t >> 7;
    const float* Ts[4] = {T0, T1, T2, T3};
    if (f < 12 && node < NN) {
        tx[localn][f] = Ts[f / 3][node * 3 + (f % 3)];
    }
    __syncthreads();
    if (node < NN) {
        float acc = bias[f];
        #pragma unroll
        for (int c = 0; c < 12; c++) acc = fmaf(tx[localn][c], Ws[c * 128 + f], acc);
        acc = acc > 0.f ? acc : 0.01f * acc;
        out[node * HD + f] = acc;
    }
}

// ---------------------------------------------------------------------------
// BatchNorm
// ---------------------------------------------------------------------------
__global__ __launch_bounds__(256) void k_bnstats(const float* __restrict__ h,
                                                 float* __restrict__ sums) {
    int f = threadIdx.x & 127;
    int r0 = blockIdx.x * 2 + (threadIdx.x >> 7);
    float s = 0.f, sq = 0.f;
    for (int r = r0; r < NN; r += 2048) {
        float v = h[r * HD + f];
        s += v;
        sq += v * v;
    }
    atomicAdd(&sums[f], s);
    atomicAdd(&sums[HD + f], sq);
}

__global__ __launch_bounds__(128) void k_bnfin(const float* __restrict__ sums,
                                               const float* __restrict__ g,
                                               const float* __restrict__ be,
                                               float* __restrict__ ss) {
    int f = threadIdx.x;
    float mean = sums[f] * (1.0f / NN);
    float var = sums[HD + f] * (1.0f / NN) - mean * mean;
    float sc = g[f] * rsqrtf(var + 1e-5f);
    ss[f] = sc;
    ss[HD + f] = be[f] - mean * sc;
}

__global__ void k_bnapply_cvt(const float* __restrict__ h, const float* __restrict__ ss,
                              unsigned short* __restrict__ out) {
    int idx = blockIdx.x * 256 + threadIdx.x;
    if (idx < NN * 32) {
        int c4 = idx & 31;
        float4 v = ((const float4*)h)[idx];
        float4 sc = ((const float4*)ss)[c4];
        float4 sh = ((const float4*)(ss + HD))[c4];
        v.x = fmaf(v.x, sc.x, sh.x);
        v.y = fmaf(v.y, sc.y, sh.y);
        v.z = fmaf(v.z, sc.z, sh.z);
        v.w = fmaf(v.w, sc.w, sh.w);
        uint2 o;
        o.x = bf2pack(v.x, v.y);
        o.y = bf2pack(v.z, v.w);
        ((uint2*)out)[idx] = o;
    }
}

// ---------------------------------------------------------------------------
// Row L2 normalize -> d_out
// ---------------------------------------------------------------------------
__global__ __launch_bounds__(256) void k_l2norm(const float* __restrict__ h,
                                                float* __restrict__ out) {
    int row = blockIdx.x * 4 + (threadIdx.x >> 6);
    int lane = threadIdx.x & 63;
    if (row >= NN) return;
    float2 v = *(const float2*)(h + row * HD + lane * 2);
    float s = v.x * v.x + v.y * v.y;
    #pragma unroll
    for (int off = 32; off > 0; off >>= 1) s += __shfl_xor(s, off);
    float scale = 1.f / fmaxf(sqrtf(s), 1e-12f);
    *(float2*)(out + row * HD + lane * 2) = make_float2(v.x * scale, v.y * scale);
}

// ---------------------------------------------------------------------------
// Launch
// ---------------------------------------------------------------------------
extern "C" void kernel_launch(void* const* d_in, const int* in_sizes, int n_in,
                              void* d_out, int out_size, void* d_ws, size_t ws_size,
                              hipStream_t stream) {
    const float* x  = (const float*)d_in[0];
    const int*   ei = (const int*)d_in[1];
    const float* W1 = (const float*)d_in[2];
    const float* b1 = (const float*)d_in[3];
    const float* W2 = (const float*)d_in[4];
    const float* b2 = (const float*)d_in[5];
    const float* W3 = (const float*)d_in[6];
    const float* b3 = (const float*)d_in[7];
    const float* W4 = (const float*)d_in[8];
    const float* b4 = (const float*)d_in[9];
    const float* g1 = (const float*)d_in[10];
    const float* be1 = (const float*)d_in[11];
    const float* g2 = (const float*)d_in[12];
    const float* be2 = (const float*)d_in[13];
    const float* g3 = (const float*)d_in[14];
    const float* be3 = (const float*)d_in[15];
    float* outp = (float*)d_out;

    char* base = (char*)d_ws;
    size_t off = 0;
    auto alloc = [&](size_t bytes) -> void* {
        void* p = base + off;
        off += (bytes + 255) & ~(size_t)255;
        return p;
    };
    float* dinv  = (float*)alloc(NN * 4);
    int*   cnt   = (int*)  alloc(NN * 4);
    int*   rowptr= (int*)  alloc((NN + 1) * 4);
    int*   bsum  = (int*)  alloc(64 * 4);
    int*   boff  = (int*)  alloc(64 * 4);
    float* bnsum = (float*)alloc(256 * 4);
    float* ss    = (float*)alloc(256 * 4);
    unsigned short* Wb = (unsigned short*)alloc(512 * 128 * 2);
    int2*  edg   = (int2*) alloc((size_t)NE * 8);
    float* T3a   = (float*)alloc(NN * 3 * 4);
    float* T3b   = (float*)alloc(NN * 3 * 4);
    float* T3c   = (float*)alloc(NN * 3 * 4);
    float* F0    = (float*)alloc((size_t)NN * HD * 4);
    unsigned short* Bb0 = (unsigned short*)alloc((size_t)NN * HD * 2);
    unsigned short* Bb1 = (unsigned short*)alloc((size_t)NN * HD * 2);
    unsigned short* Bb2 = (unsigned short*)alloc((size_t)NN * HD * 2);
    unsigned short* Bb3 = (unsigned short*)alloc((size_t)NN * HD * 2);

    // overlays (consumed before their host slabs are first written):
    // pre[NSL][25000] u32 = 12.8 MB on F0 (25.6 MB); phist 25.6 MB on Bb0+Bb1.
    unsigned* pre   = (unsigned*)F0;
    unsigned* phist = (unsigned*)Bb0;

    const int gN = (NN + 255) / 256;
    const int nb = (NN + 1023) / 1024;

    // ---- graph prep (no global atomics) ----
    k_hist<<<512, 256, 0, stream>>>(ei, phist);
    k_hreduce<<<(50000 + 255) / 256, 256, 0, stream>>>(phist, dinv, cnt, pre);
    k_scan1<<<nb, 1024, 0, stream>>>(cnt, rowptr, bsum);
    k_scan2<<<1, 64, 0, stream>>>(bsum, boff, nb, rowptr);
    k_scan3<<<gN, 256, 0, stream>>>(rowptr, boff);
    k_fill2<<<256, 256, 0, stream>>>(ei, dinv, rowptr, pre, edg);

    const int gP = NN / 16;
    const int gG = 625;
    const int gApply = (NN * 32 + 255) / 256;
    const int gL2 = (NN + 3) / 4;

    // ---- layer 1 (in: x [N,3], fp32) ----
    k_prop3<<<gN, 256, 0, stream>>>(x, nullptr, rowptr, edg, T3a);
    k_prop3<<<gN, 256, 0, stream>>>(T3a, x, rowptr, edg, T3b);
    k_prop3<<<gN, 256, 0, stream>>>(T3b, T3a, rowptr, edg, T3c);
    k_gemm1<<<(NN * 128 + 255) / 256, 256, 0, stream>>>(x, T3a, T3b, T3c, W1, b1, F0);
    hipMemsetAsync(bnsum, 0, 256 * 4, stream);
    k_bnstats<<<1024, 256, 0, stream>>>(F0, bnsum);
    k_bnfin<<<1, 128, 0, stream>>>(bnsum, g1, be1, ss);
    k_bnapply_cvt<<<gApply, 256, 0, stream>>>(F0, ss, Bb0);

    // ---- layer 2 ----
    k_wconv<<<256, 256, 0, stream>>>(W2, Wb);
    k_prop_bf<<<gP, 256, 0, stream>>>(Bb0, nullptr, rowptr, edg, Bb1);
    k_prop_bf<<<gP, 256, 0, stream>>>(Bb1, Bb0, rowptr, edg, Bb2);
    k_prop_bf<<<gP, 256, 0, stream>>>(Bb2, Bb1, rowptr, edg, Bb3);
    hipMemsetAsync(bnsum, 0, 256 * 4, stream);
    k_gemmM<<<gG, 256, 0, stream>>>(Bb0, Bb1, Bb2, Bb3, Wb, b2, F0, 1, bnsum);
    k_bnfin<<<1, 128, 0, stream>>>(bnsum, g2, be2, ss);
    k_bnapply_cvt<<<gApply, 256, 0, stream>>>(F0, ss, Bb0);

    // ---- layer 3 ----
    k_wconv<<<256, 256, 0, stream>>>(W3, Wb);
    k_prop_bf<<<gP, 256, 0, stream>>>(Bb0, nullptr, rowptr, edg, Bb1);
    k_prop_bf<<<gP, 256, 0, stream>>>(Bb1, Bb0, rowptr, edg, Bb2);
    k_prop_bf<<<gP, 256, 0, stream>>>(Bb2, Bb1, rowptr, edg, Bb3);
    hipMemsetAsync(bnsum, 0, 256 * 4, stream);
    k_gemmM<<<gG, 256, 0, stream>>>(Bb0, Bb1, Bb2, Bb3, Wb, b3, F0, 2, bnsum);
    k_bnfin<<<1, 128, 0, stream>>>(bnsum, g3, be3, ss);
    k_bnapply_cvt<<<gApply, 256, 0, stream>>>(F0, ss, Bb0);

    // ---- layer 4 ----
    k_wconv<<<256, 256, 0, stream>>>(W4, Wb);
    k_prop_bf<<<gP, 256, 0, stream>>>(Bb0, nullptr, rowptr, edg, Bb1);
    k_prop_bf<<<gP, 256, 0, stream>>>(Bb1, Bb0, rowptr, edg, Bb2);
    k_prop_bf<<<gP, 256, 0, stream>>>(Bb2, Bb1, rowptr, edg, Bb3);
    k_gemmM<<<gG, 256, 0, stream>>>(Bb0, Bb1, Bb2, Bb3, Wb, b4, F0, 0, nullptr);
    k_l2norm<<<gL2, 256, 0, stream>>>(F0, outp);

    (void)n_in; (void)in_sizes; (void)out_size; (void)ws_size;
}